// Round 8
// baseline (244.909 us; speedup 1.0000x reference)
//
#include <hip/hip_runtime.h>

// Collapsed problem (channel-sum commutes with the linear conv):
//   out[n,d,h,w] = sum_{i,kd,kh,kw} x[n,i,d+kd,h+kh,w+kw] * Wsum[i,kd,kh,kw] + C
//   Wsum = 0.5 * sum_o conv_weight[o,...]   (32*27 = 864 floats)
//   C    = sum_o (0.5*conv_bias[o] + bias[o])
// x: (8,32,32,64,64) fp32; out: (8,30,62,62) fp32.
//
// R8: REGISTER-DIRECT bisect — no LDS for x, no global_load_lds, no barriers
// in the channel loop. Each thread owns 1d x 1h x 4w outputs; per channel it
// loads its 9 row-strips (3 slices x 3 rows) as one dwordx4 each straight to
// VGPRs (octet-coalesced: 8 consecutive lanes cover 128B of one row); the
// 2-float w-halo comes from lane+1 via DPP row_shl:1 (verified in R7).
// Cross-thread halo reuse (~2x) is served by L1/L2 instead of LDS.
// Parallelism doubled: 4096 waves = 16 waves/CU = 4/SIMD (vs 19% occ in R7).

#define XD 32
#define XH 64
#define XW 64
#define DOUT 30
#define HOUT 62
#define WOUT 62
#define CH_STRIDE (XD * XH * XW)

__device__ __forceinline__ float nextlane(float v) {
  // row_shl:1 -> lane i gets lane i+1 (within 16-lane row); bound_ctrl=true:
  // lane 15/31/47/63 read 0 -> feeds only epilogue-masked outputs (s=15).
  return __int_as_float(
      __builtin_amdgcn_mov_dpp(__float_as_int(v), 0x101, 0xF, 0xF, true));
}

__global__ __launch_bounds__(256, 4)
void conv3d_chansum_reg(const float* __restrict__ x,
                        const float* __restrict__ cw,
                        const float* __restrict__ cb,
                        const float* __restrict__ pb,
                        float* __restrict__ out) {
  // weights: [32 ch][48: 3 kd-blocks of 16 (9 taps + pad, 16B-aligned)] + C
  __shared__ float wl[1537];

  const int tid  = threadIdx.x;
  const int wid  = tid >> 6;
  const int lane = tid & 63;

  // XCD-aware swizzle (1024 % 8 == 0 -> bijective): consecutive logical
  // blocks (same n, nearby d) share x in one XCD's L2.
  const int bid = blockIdx.x;
  const int swz = (bid & 7) * 128 + (bid >> 3);

  const int wslab = swz * 4 + wid;    // 0..4095
  const int n  = wslab >> 9;          // 0..7
  const int d  = (wslab >> 4) & 31;   // 0..31 (30,31 dead)
  const int h0 = (wslab & 15) * 4;

  const int s  = lane & 15;           // w-strip: w0 = 4s
  const int ht = lane >> 4;           // 0..3
  const bool alive = d < DOUT;        // wave-uniform

  // ---- prologue: Wsum via float4 (864 = 216*4), C via wave-0 reduce ----
  if (tid < 216) {
    const float4* cw4 = (const float4*)(cw + 4 * tid);
    float4 sum = {0.f, 0.f, 0.f, 0.f};
#pragma unroll 8
    for (int o = 0; o < 64; ++o) {
      float4 v = cw4[o * 216];   // cw + o*864 + 4*tid
      sum.x += v.x; sum.y += v.y; sum.z += v.z; sum.w += v.w;
    }
    float vs[4] = {sum.x, sum.y, sum.z, sum.w};
#pragma unroll
    for (int q = 0; q < 4; ++q) {
      int e  = 4 * tid + q;      // e = i*27 + kd*9 + t
      int i  = e / 27;
      int r  = e - i * 27;
      int kd = r / 9;
      int t  = r - kd * 9;
      wl[i * 48 + kd * 16 + t] = 0.5f * vs[q];
    }
  }
  if (tid < 64) {
    float v = 0.5f * cb[tid] + pb[tid];
#pragma unroll
    for (int off = 32; off > 0; off >>= 1) v += __shfl_xor(v, off, 64);
    if (tid == 0) wl[1536] = v;
  }
  __syncthreads();   // only barrier in the kernel
  if (!alive) return;

  const float* xn = x + (size_t)n * (32u * CH_STRIDE);

  // 9 channel-invariant strip offsets; h clamped (clamped rows only feed
  // masked outputs h>=62 — valid output h needs rows h..h+2 <= 63).
  int soff[9];
#pragma unroll
  for (int kd = 0; kd < 3; ++kd)
#pragma unroll
    for (int kh = 0; kh < 3; ++kh) {
      int rc = min(h0 + ht + kh, XH - 1);
      soff[kd * 3 + kh] = (d + kd) * (XH * XW) + rc * XW + 4 * s;
    }

  float acc[4] = {0.f, 0.f, 0.f, 0.f};

#pragma unroll 1
  for (int ch = 0; ch < 32; ++ch) {
    const float* xnc = xn + (size_t)ch * CH_STRIDE;

    // issue all 9 strip loads up front (static indices -> stay in VGPRs)
    float4 a[9];
#pragma unroll
    for (int i = 0; i < 9; ++i)
      a[i] = *(const float4*)(xnc + soff[i]);

    const float* wrow = &wl[ch * 48];
#pragma unroll
    for (int kd = 0; kd < 3; ++kd) {
      // 9 taps of this kd-block: two aligned b128 broadcasts + one b32
      float4 w0 = *(const float4*)(wrow + kd * 16);
      float4 w1 = *(const float4*)(wrow + kd * 16 + 4);
      float  w8 = wrow[kd * 16 + 8];
      float wt[9] = {w0.x, w0.y, w0.z, w0.w, w1.x, w1.y, w1.z, w1.w, w8};
#pragma unroll
      for (int kh = 0; kh < 3; ++kh) {
        float4 av = a[kd * 3 + kh];
        float x4v = nextlane(av.x);   // w0+4 from lane+1
        float x5v = nextlane(av.y);   // w0+5 from lane+1
        float xv[6] = {av.x, av.y, av.z, av.w, x4v, x5v};
#pragma unroll
        for (int j = 0; j < 4; ++j)
          acc[j] = fmaf(xv[j],     wt[kh * 3 + 0],
                   fmaf(xv[j + 1], wt[kh * 3 + 1],
                   fmaf(xv[j + 2], wt[kh * 3 + 2], acc[j])));
      }
    }
  }

  // epilogue: out[n][d][h0+ht][4s..4s+3]; nw is 4, or 2 when s==15
  const float Cc = wl[1536];
  const int h = h0 + ht;
  if (h < HOUT) {
    float* op = out + (((size_t)n * DOUT + d) * HOUT + h) * WOUT + 4 * s;
    const int nw = min(4, WOUT - 4 * s);
    float2 v0 = {acc[0] + Cc, acc[1] + Cc};
    *(float2*)op = v0;                       // 8B-aligned: (even)*4B
    if (nw == 4) {
      float2 v1 = {acc[2] + Cc, acc[3] + Cc};
      *(float2*)(op + 2) = v1;
    }
  }
}

extern "C" void kernel_launch(void* const* d_in, const int* in_sizes, int n_in,
                              void* d_out, int out_size, void* d_ws, size_t ws_size,
                              hipStream_t stream) {
  const float* x  = (const float*)d_in[0];  // (8,32,32,64,64)
  const float* cw = (const float*)d_in[1];  // (64,32,3,3,3)
  const float* cb = (const float*)d_in[2];  // (64,)
  const float* pb = (const float*)d_in[3];  // (64,1,1,1)
  float* out = (float*)d_out;               // (8,30,62,62)

  conv3d_chansum_reg<<<dim3(1024), 256, 0, stream>>>(x, cw, cb, pb, out);
}